// Round 4
// baseline (500.579 us; speedup 1.0000x reference)
//
#include <hip/hip_runtime.h>
#include <math.h>

#define CAP 96          // max in-degree stored; Poisson(16) tail beyond 96 ~ 1e-42
#define XS 68           // Xt LDS stride: b128-aligned, caps staging conflict at 4-way
#define NR 13           // dst ranges: d>>13, 100000/8192 -> 13 ranges (3.1 MB bucket slice/range)
#define EPB 4096        // edges per partition block (16/thread)

typedef unsigned int uint;
typedef unsigned short ushort;

__device__ __forceinline__ ushort f2bf(float f) {   // RNE fp32 -> bf16
  union { float f; uint u; } v; v.f = f;
  uint u = v.u;
  return (ushort)((u + 0x7fffu + ((u >> 16) & 1u)) >> 16);
}
__device__ __forceinline__ float bflo(uint p) {
  union { uint u; float f; } v; v.u = p << 16; return v.f;
}
__device__ __forceinline__ float bfhi(uint p) {
  union { uint u; float f; } v; v.u = p & 0xffff0000u; return v.f;
}

// ---------------- edge partition by dst range ----------------

__global__ __launch_bounds__(256) void k_hist(const int* __restrict__ dst,
                                              int* __restrict__ aux, int E) {
  __shared__ int h[NR];
  if (threadIdx.x < NR) h[threadIdx.x] = 0;
  __syncthreads();
  for (int e = blockIdx.x * 256 + threadIdx.x; e < E; e += gridDim.x * 256)
    atomicAdd(&h[dst[e] >> 13], 1);
  __syncthreads();
  if (threadIdx.x < NR) atomicAdd(aux + threadIdx.x, h[threadIdx.x]);
}

__global__ void k_scan(int* __restrict__ aux) {
  if (threadIdx.x == 0) {
    int run = 0;
    for (int r = 0; r < NR; ++r) { int v = aux[r]; aux[r] = run; run += v; }
  }
}

// Scatter edges into NR dst-range streams. Block-local LDS ranking, 13 cursor
// atomics per block. Output: part[] of int2{src,dst}, range-contiguous.
__global__ __launch_bounds__(256) void k_partition(const int* __restrict__ src,
    const int* __restrict__ dst, int* __restrict__ cursor,
    int2* __restrict__ part, int E) {
  __shared__ int lcnt[NR * 256];
  __shared__ int basev[NR];
  const int t = threadIdx.x;
  const int b0 = blockIdx.x * EPB;
  for (int r = 0; r < NR; ++r) lcnt[r * 256 + t] = 0;
  __syncthreads();
  int es[16], ed[16];
  #pragma unroll
  for (int j = 0; j < 16; ++j) {
    int e = b0 + j * 256 + t;
    int d = (e < E) ? dst[e] : -1;
    es[j] = (e < E) ? src[e] : 0;
    ed[j] = d;
    if (d >= 0) lcnt[(d >> 13) * 256 + t]++;     // only thread t touches column t
  }
  __syncthreads();
  if (t < NR) {                                   // exclusive scan over threads
    int run = 0;
    #pragma unroll 8
    for (int k = 0; k < 256; ++k) { int v = lcnt[t * 256 + k]; lcnt[t * 256 + k] = run; run += v; }
    basev[t] = atomicAdd(cursor + t, run);
  }
  __syncthreads();
  #pragma unroll
  for (int j = 0; j < 16; ++j) {
    int d = ed[j];
    if (d >= 0) {
      int r = d >> 13;
      int off = lcnt[r * 256 + t]++;              // per-(r,t) running cursor
      part[basev[r] + off] = make_int2(es[j], d);
    }
  }
}

// Bucket build over the partitioned stream: dst confined to one 8192-node range
// per region of part[] -> cnt/bucket slices stay hot in L2, stores merge.
__global__ __launch_bounds__(256) void k_bucket2(const int2* __restrict__ part,
    int* __restrict__ cnt, int* __restrict__ bucket, int E) {
  int e = blockIdx.x * 256 + threadIdx.x;
  if (e >= E) return;
  int2 p = part[e];
  int k = atomicAdd(cnt + p.y, 1);
  if (k < CAP) bucket[(size_t)p.y * CAP + k] = p.x;
}

__global__ __launch_bounds__(256) void k_dinv(const int* __restrict__ cnt,
                                              float* __restrict__ dinv, int n) {
  int i = blockIdx.x * 256 + threadIdx.x;
  if (i < n) dinv[i] = rsqrtf((float)cnt[i] + 1.0f);   // +1 self-loop
}

// ---------------- fp32 GEMM -> bf16 prescaled rows ----------------
// H[node][j] = (X[node][:] . W[:][j]) * dinv[node], bf16.

__global__ __launch_bounds__(256) void k_gemm_bf(const float* __restrict__ X,
    const float* __restrict__ W, const float* __restrict__ dinv,
    ushort* __restrict__ H, int n, int ntiles) {
  __shared__ float Wl[128 * 64];
  __shared__ float Xt[128 * XS];
  const int t = threadIdx.x;
  const int colhalf = blockIdx.x & 1;

  for (int i = t; i < 2048; i += 256) {
    int k = i >> 4, j4 = i & 15;
    ((float4*)Wl)[i] = *(const float4*)(W + k * 128 + colhalf * 64 + j4 * 4);
  }
  const int cg = t & 15;
  const int ng = t >> 4;
  const int stride = gridDim.x >> 1;

  for (int tile = blockIdx.x >> 1; tile < ntiles; tile += stride) {
    int base = tile * 64;
    __syncthreads();
    for (int i = t; i < 2048; i += 256) {
      int node = i >> 5;
      int k4 = (i & 31) * 4;
      float4 v = make_float4(0.f, 0.f, 0.f, 0.f);
      if (base + node < n) v = *(const float4*)(X + (size_t)(base + node) * 128 + k4);
      Xt[(k4 + 0) * XS + node] = v.x;
      Xt[(k4 + 1) * XS + node] = v.y;
      Xt[(k4 + 2) * XS + node] = v.z;
      Xt[(k4 + 3) * XS + node] = v.w;
    }
    __syncthreads();

    float a00=0,a01=0,a02=0,a03=0, a10=0,a11=0,a12=0,a13=0;
    float a20=0,a21=0,a22=0,a23=0, a30=0,a31=0,a32=0,a33=0;
    #pragma unroll 8
    for (int k = 0; k < 128; ++k) {
      float4 xv = *(const float4*)&Xt[k * XS + ng * 4];
      float4 wv = *(const float4*)&Wl[k * 64 + cg * 4];
      a00 += xv.x*wv.x; a01 += xv.x*wv.y; a02 += xv.x*wv.z; a03 += xv.x*wv.w;
      a10 += xv.y*wv.x; a11 += xv.y*wv.y; a12 += xv.y*wv.z; a13 += xv.y*wv.w;
      a20 += xv.z*wv.x; a21 += xv.z*wv.y; a22 += xv.z*wv.z; a23 += xv.z*wv.w;
      a30 += xv.w*wv.x; a31 += xv.w*wv.y; a32 += xv.w*wv.z; a33 += xv.w*wv.w;
    }

    size_t cbase = (size_t)colhalf * 64 + cg * 4;
    int n0 = base + ng * 4;
    float r[4][4] = {{a00,a01,a02,a03},{a10,a11,a12,a13},
                     {a20,a21,a22,a23},{a30,a31,a32,a33}};
    #pragma unroll
    for (int q = 0; q < 4; ++q) {
      if (n0 + q < n) {
        float dv = dinv[n0 + q];
        ushort4 o;
        o.x = f2bf(r[q][0] * dv); o.y = f2bf(r[q][1] * dv);
        o.z = f2bf(r[q][2] * dv); o.w = f2bf(r[q][3] * dv);
        *(ushort4*)(H + (size_t)(n0 + q) * 128 + cbase) = o;
      }
    }
  }
}

// ---------------- aggregation: 4 nodes/wave, 16 lanes x dwordx4 per row ----------------
// One vmem instruction gathers 4 rows (one per 16-lane group); unroll 4 -> 16 rows in flight.
// Rows prescaled by dinv[src]: OUT[d] = tanh(dinv[d]*sum(rows) + b).

__device__ __forceinline__ void acc8(float* a, uint4 v, bool act) {
  if (act) {
    a[0] += bflo(v.x); a[1] += bfhi(v.x); a[2] += bflo(v.y); a[3] += bfhi(v.y);
    a[4] += bflo(v.z); a[5] += bfhi(v.z); a[6] += bflo(v.w); a[7] += bfhi(v.w);
  }
}

template <bool FC>
__global__ __launch_bounds__(256) void k_agg4(const ushort* __restrict__ H,
    const int* __restrict__ cnt, const int* __restrict__ bucket,
    const float* __restrict__ dinv, const float* __restrict__ bias,
    const float* __restrict__ Wfc, const float* __restrict__ bfc,
    float* __restrict__ OUT, float* __restrict__ OUTV, int n) {
  const int wave = (blockIdx.x * 256 + threadIdx.x) >> 6;
  const int lane = threadIdx.x & 63;
  const int g = lane >> 4, sub = lane & 15;
  const int node = wave * 4 + g;
  const bool an = node < n;
  const int nc = an ? node : 0;
  const uint4* H4 = (const uint4*)H;          // row = 16 x uint4 (8 bf16 each)

  uint4 v = H4[(size_t)nc * 16 + sub];        // own (prescaled) row
  float a[8] = {bflo(v.x),bfhi(v.x),bflo(v.y),bfhi(v.y),
                bflo(v.z),bfhi(v.z),bflo(v.w),bfhi(v.w)};
  int c = an ? min(cnt[nc], CAP) : 0;
  int cmax = max(c, __shfl_xor(c, 16)); cmax = max(cmax, __shfl_xor(cmax, 32));
  const int* bk = bucket + (size_t)nc * CAP;

  int i = 0;
  for (; i + 4 <= cmax; i += 4) {
    int s0 = (i     < c) ? bk[i]     : nc;
    int s1 = (i + 1 < c) ? bk[i + 1] : nc;
    int s2 = (i + 2 < c) ? bk[i + 2] : nc;
    int s3 = (i + 3 < c) ? bk[i + 3] : nc;
    uint4 v0 = H4[(size_t)s0 * 16 + sub];
    uint4 v1 = H4[(size_t)s1 * 16 + sub];
    uint4 v2 = H4[(size_t)s2 * 16 + sub];
    uint4 v3 = H4[(size_t)s3 * 16 + sub];
    acc8(a, v0, i < c); acc8(a, v1, i + 1 < c);
    acc8(a, v2, i + 2 < c); acc8(a, v3, i + 3 < c);
  }
  for (; i < cmax; ++i) {
    int s = (i < c) ? bk[i] : nc;
    uint4 v0 = H4[(size_t)s * 16 + sub];
    acc8(a, v0, i < c);
  }

  float dn = an ? dinv[nc] : 0.f;
  float4 b0 = ((const float4*)bias)[sub * 2];
  float4 b1 = ((const float4*)bias)[sub * 2 + 1];
  float o[8];
  o[0] = tanhf(a[0]*dn + b0.x); o[1] = tanhf(a[1]*dn + b0.y);
  o[2] = tanhf(a[2]*dn + b0.z); o[3] = tanhf(a[3]*dn + b0.w);
  o[4] = tanhf(a[4]*dn + b1.x); o[5] = tanhf(a[5]*dn + b1.y);
  o[6] = tanhf(a[6]*dn + b1.z); o[7] = tanhf(a[7]*dn + b1.w);
  if (an) {
    float4* dst0 = (float4*)(OUT + (size_t)node * 128 + sub * 8);
    dst0[0] = make_float4(o[0], o[1], o[2], o[3]);
    dst0[1] = make_float4(o[4], o[5], o[6], o[7]);
  }
  if (FC) {
    float4 w0 = ((const float4*)Wfc)[sub * 2];
    float4 w1 = ((const float4*)Wfc)[sub * 2 + 1];
    float p = o[0]*w0.x + o[1]*w0.y + o[2]*w0.z + o[3]*w0.w
            + o[4]*w1.x + o[5]*w1.y + o[6]*w1.z + o[7]*w1.w;
    p += __shfl_down(p, 8, 16);
    p += __shfl_down(p, 4, 16);
    p += __shfl_down(p, 2, 16);
    p += __shfl_down(p, 1, 16);
    if (an && sub == 0) OUTV[node] = 1.0f / (1.0f + expf(-(p + bfc[0])));
  }
}

// ---------------- launch ----------------

extern "C" void kernel_launch(void* const* d_in, const int* in_sizes, int n_in,
                              void* d_out, int out_size, void* d_ws, size_t ws_size,
                              hipStream_t stream) {
  const float* x   = (const float*)d_in[0];
  const int*   ei  = (const int*)d_in[1];
  const float* W1  = (const float*)d_in[2];
  const float* b1  = (const float*)d_in[3];
  const float* W2  = (const float*)d_in[4];
  const float* b2  = (const float*)d_in[5];
  const float* Wfc = (const float*)d_in[6];
  const float* bfc = (const float*)d_in[7];

  const int N = in_sizes[0] / 128;
  const int E = in_sizes[1] / 2;
  const int* src = ei;
  const int* dst = ei + E;

  float* out = (float*)d_out;      // [N] sigmoid output
  float* emb = out + N;            // [N*128] embeddings; doubles as layer-1 act scratch

  char* ws = (char*)d_ws;
  auto take = [&](size_t bytes) { char* p = ws; ws += (bytes + 255) & ~(size_t)255; return p; };
  int*    cnt    = (int*)   take((size_t)N * 4);
  float*  dinv   = (float*) take((size_t)N * 4);
  int*    aux    = (int*)   take(64 * 4);
  int*    bucket = (int*)   take((size_t)N * CAP * 4);
  ushort* bufH   = (ushort*)take((size_t)N * 128 * 2);   // bf16 h*dinv
  // part[] aliases bufH: consumed by k_bucket2 strictly before gemm writes bufH
  int2*   part   = (int2*)bufH;

  const int ntiles = (N + 63) / 64;
  const int aggBlocks = (N + 15) / 16;     // 16 nodes per 256-thread block

  hipMemsetAsync(cnt, 0, (size_t)N * 4, stream);
  hipMemsetAsync(aux, 0, 64 * 4, stream);

  k_hist<<<1024, 256, 0, stream>>>(dst, aux, E);
  k_scan<<<1, 64, 0, stream>>>(aux);
  k_partition<<<(E + EPB - 1) / EPB, 256, 0, stream>>>(src, dst, aux, part, E);
  k_bucket2<<<(E + 255) / 256, 256, 0, stream>>>(part, cnt, bucket, E);
  k_dinv<<<(N + 255) / 256, 256, 0, stream>>>(cnt, dinv, N);

  // layer 1
  k_gemm_bf<<<1024, 256, 0, stream>>>(x, W1, dinv, bufH, N, ntiles);
  k_agg4<false><<<aggBlocks, 256, 0, stream>>>(bufH, cnt, bucket, dinv, b1,
                                               nullptr, nullptr, emb, nullptr, N);
  // layer 2 (+ fused FC head)
  k_gemm_bf<<<1024, 256, 0, stream>>>(emb, W2, dinv, bufH, N, ntiles);
  k_agg4<true><<<aggBlocks, 256, 0, stream>>>(bufH, cnt, bucket, dinv, b2,
                                              Wfc, bfc, emb, out, N);
}

// Round 5
// 437.554 us; speedup vs baseline: 1.1440x; 1.1440x over previous
//
#include <hip/hip_runtime.h>
#include <math.h>

#define CAP 96          // max in-degree stored; Poisson(16) tail beyond 96 ~ 1e-42
#define NR 13           // dst ranges: d>>13 -> 13 ranges (3.1 MB bucket slice/range)
#define EPB 4096        // edges per partition block (16/thread)

typedef unsigned int uint;
typedef unsigned short ushort;
typedef __attribute__((ext_vector_type(8))) short bf16x8;
typedef __attribute__((ext_vector_type(4))) float f32x4;

__device__ __forceinline__ ushort f2bf(float f) {   // RNE fp32 -> bf16
  union { float f; uint u; } v; v.f = f;
  uint u = v.u;
  return (ushort)((u + 0x7fffu + ((u >> 16) & 1u)) >> 16);
}
__device__ __forceinline__ float bflo(uint p) {
  union { uint u; float f; } v; v.u = p << 16; return v.f;
}
__device__ __forceinline__ float bfhi(uint p) {
  union { uint u; float f; } v; v.u = p & 0xffff0000u; return v.f;
}
__device__ __forceinline__ uint pk2(float a, float b) {      // pack 2 bf16
  return (uint)f2bf(a) | ((uint)f2bf(b) << 16);
}
__device__ __forceinline__ uint pk2r(float a, float b, float& ra, float& rb) {
  ushort ha = f2bf(a), hb = f2bf(b);
  union { uint u; float f; } va, vb;
  va.u = (uint)ha << 16; vb.u = (uint)hb << 16;
  ra = a - va.f; rb = b - vb.f;                              // exact residuals
  return (uint)ha | ((uint)hb << 16);
}

// ---------------- edge partition by dst range ----------------

__global__ __launch_bounds__(256) void k_hist(const int* __restrict__ dst,
                                              int* __restrict__ aux, int E) {
  __shared__ int h[NR];
  if (threadIdx.x < NR) h[threadIdx.x] = 0;
  __syncthreads();
  for (int e = blockIdx.x * 256 + threadIdx.x; e < E; e += gridDim.x * 256)
    atomicAdd(&h[dst[e] >> 13], 1);
  __syncthreads();
  if (threadIdx.x < NR) atomicAdd(aux + threadIdx.x, h[threadIdx.x]);
}

__global__ void k_scan(int* __restrict__ aux) {
  if (threadIdx.x == 0) {
    int run = 0;
    for (int r = 0; r < NR; ++r) { int v = aux[r]; aux[r] = run; run += v; }
  }
}

__global__ __launch_bounds__(256) void k_partition(const int* __restrict__ src,
    const int* __restrict__ dst, int* __restrict__ cursor,
    int2* __restrict__ part, int E) {
  __shared__ int lcnt[NR * 256];
  __shared__ int basev[NR];
  const int t = threadIdx.x;
  const int b0 = blockIdx.x * EPB;
  for (int r = 0; r < NR; ++r) lcnt[r * 256 + t] = 0;
  __syncthreads();
  int es[16], ed[16];
  #pragma unroll
  for (int j = 0; j < 16; ++j) {
    int e = b0 + j * 256 + t;
    int d = (e < E) ? dst[e] : -1;
    es[j] = (e < E) ? src[e] : 0;
    ed[j] = d;
    if (d >= 0) lcnt[(d >> 13) * 256 + t]++;
  }
  __syncthreads();
  if (t < NR) {
    int run = 0;
    #pragma unroll 8
    for (int k = 0; k < 256; ++k) { int v = lcnt[t * 256 + k]; lcnt[t * 256 + k] = run; run += v; }
    basev[t] = atomicAdd(cursor + t, run);
  }
  __syncthreads();
  #pragma unroll
  for (int j = 0; j < 16; ++j) {
    int d = ed[j];
    if (d >= 0) {
      int r = d >> 13;
      int off = lcnt[r * 256 + t]++;
      part[basev[r] + off] = make_int2(es[j], d);
    }
  }
}

__global__ __launch_bounds__(256) void k_bucket2(const int2* __restrict__ part,
    int* __restrict__ cnt, int* __restrict__ bucket, int E) {
  int e = blockIdx.x * 256 + threadIdx.x;
  if (e >= E) return;
  int2 p = part[e];
  int k = atomicAdd(cnt + p.y, 1);
  if (k < CAP) bucket[(size_t)p.y * CAP + k] = p.x;
}

__global__ __launch_bounds__(256) void k_dinv(const int* __restrict__ cnt,
                                              float* __restrict__ dinv, int n) {
  int i = blockIdx.x * 256 + threadIdx.x;
  if (i < n) dinv[i] = rsqrtf((float)cnt[i] + 1.0f);   // +1 self-loop
}

// ---------------- MFMA GEMM: H = (X @ W) * dinv[row], bf16 out ----------------
// One wave per 16-node tile. W-frags in 128 VGPRs (loaded once per wave from
// L2-hot W). A loaded straight from global (coalesced dwordx4), hi/lo bf16
// split for fp32-grade A precision. No LDS, no barriers, no bank conflicts.
// mfma_f32_16x16x32_bf16: A[m=sub][k=quad*8+j], B[k=quad*8+j][n=sub],
// D col=sub, row=quad*4+reg (m89/m120 verified layouts).

__global__ __launch_bounds__(256) void k_gemm_mfma(const float* __restrict__ X,
    const float* __restrict__ W, const float* __restrict__ dinv,
    ushort* __restrict__ H, int n, int ntiles) {
  const int lane = threadIdx.x & 63;
  const int quad = lane >> 4;
  const int sub  = lane & 15;
  const int wid    = (blockIdx.x * 256 + threadIdx.x) >> 6;
  const int nwaves = (gridDim.x * 256) >> 6;

  // W fragments -> registers: Bh[ki][ct], k = ki*32 + quad*8 + j, col = ct*16 + sub
  union { bf16x8 v; uint u[4]; } Bh[4][8];
  #pragma unroll
  for (int ki = 0; ki < 4; ++ki) {
    #pragma unroll
    for (int ct = 0; ct < 8; ++ct) {
      const float* wp = W + (ki * 32 + quad * 8) * 128 + ct * 16 + sub;
      Bh[ki][ct].u[0] = pk2(wp[0],   wp[128]);
      Bh[ki][ct].u[1] = pk2(wp[256], wp[384]);
      Bh[ki][ct].u[2] = pk2(wp[512], wp[640]);
      Bh[ki][ct].u[3] = pk2(wp[768], wp[896]);
    }
  }

  for (int tile = wid; tile < ntiles; tile += nwaves) {
    int base = tile * 16;
    int row  = base + sub;                       // A row this lane reads
    if (row >= n) row = n - 1;                   // clamp (tail safety)
    const float* xp = X + (size_t)row * 128 + quad * 8;

    f32x4 acc[8];
    #pragma unroll
    for (int ct = 0; ct < 8; ++ct) acc[ct] = (f32x4){0.f, 0.f, 0.f, 0.f};

    #pragma unroll
    for (int ki = 0; ki < 4; ++ki) {
      float4 xa = *(const float4*)(xp + ki * 32);
      float4 xb = *(const float4*)(xp + ki * 32 + 4);
      union { bf16x8 v; uint u[4]; } ah, al;
      float r0,r1,r2,r3,r4,r5,r6,r7;
      ah.u[0] = pk2r(xa.x, xa.y, r0, r1);
      ah.u[1] = pk2r(xa.z, xa.w, r2, r3);
      ah.u[2] = pk2r(xb.x, xb.y, r4, r5);
      ah.u[3] = pk2r(xb.z, xb.w, r6, r7);
      al.u[0] = pk2(r0, r1);
      al.u[1] = pk2(r2, r3);
      al.u[2] = pk2(r4, r5);
      al.u[3] = pk2(r6, r7);
      #pragma unroll
      for (int ct = 0; ct < 8; ++ct) {
        acc[ct] = __builtin_amdgcn_mfma_f32_16x16x32_bf16(ah.v, Bh[ki][ct].v, acc[ct], 0, 0, 0);
        acc[ct] = __builtin_amdgcn_mfma_f32_16x16x32_bf16(al.v, Bh[ki][ct].v, acc[ct], 0, 0, 0);
      }
    }

    float dv[4];
    #pragma unroll
    for (int r = 0; r < 4; ++r) {
      int rr = base + quad * 4 + r;
      dv[r] = (rr < n) ? dinv[rr] : 0.f;
    }
    #pragma unroll
    for (int ct = 0; ct < 8; ++ct) {
      #pragma unroll
      for (int r = 0; r < 4; ++r) {
        int rr = base + quad * 4 + r;
        if (rr < n)
          H[(size_t)rr * 128 + ct * 16 + sub] = f2bf(acc[ct][r] * dv[r]);
      }
    }
  }
}

// ---------------- aggregation: 4 nodes/wave, 16 lanes x dwordx4 per row ----------------

__device__ __forceinline__ void acc8(float* a, uint4 v, bool act) {
  if (act) {
    a[0] += bflo(v.x); a[1] += bfhi(v.x); a[2] += bflo(v.y); a[3] += bfhi(v.y);
    a[4] += bflo(v.z); a[5] += bfhi(v.z); a[6] += bflo(v.w); a[7] += bfhi(v.w);
  }
}

template <bool FC>
__global__ __launch_bounds__(256) void k_agg4(const ushort* __restrict__ H,
    const int* __restrict__ cnt, const int* __restrict__ bucket,
    const float* __restrict__ dinv, const float* __restrict__ bias,
    const float* __restrict__ Wfc, const float* __restrict__ bfc,
    float* __restrict__ OUT, float* __restrict__ OUTV, int n) {
  const int wave = (blockIdx.x * 256 + threadIdx.x) >> 6;
  const int lane = threadIdx.x & 63;
  const int g = lane >> 4, sub = lane & 15;
  const int node = wave * 4 + g;
  const bool an = node < n;
  const int nc = an ? node : 0;
  const uint4* H4 = (const uint4*)H;

  uint4 v = H4[(size_t)nc * 16 + sub];
  float a[8] = {bflo(v.x),bfhi(v.x),bflo(v.y),bfhi(v.y),
                bflo(v.z),bfhi(v.z),bflo(v.w),bfhi(v.w)};
  int c = an ? min(cnt[nc], CAP) : 0;
  int cmax = max(c, __shfl_xor(c, 16)); cmax = max(cmax, __shfl_xor(cmax, 32));
  const int* bk = bucket + (size_t)nc * CAP;

  int i = 0;
  for (; i + 4 <= cmax; i += 4) {
    int s0 = (i     < c) ? bk[i]     : nc;
    int s1 = (i + 1 < c) ? bk[i + 1] : nc;
    int s2 = (i + 2 < c) ? bk[i + 2] : nc;
    int s3 = (i + 3 < c) ? bk[i + 3] : nc;
    uint4 v0 = H4[(size_t)s0 * 16 + sub];
    uint4 v1 = H4[(size_t)s1 * 16 + sub];
    uint4 v2 = H4[(size_t)s2 * 16 + sub];
    uint4 v3 = H4[(size_t)s3 * 16 + sub];
    acc8(a, v0, i < c); acc8(a, v1, i + 1 < c);
    acc8(a, v2, i + 2 < c); acc8(a, v3, i + 3 < c);
  }
  for (; i < cmax; ++i) {
    int s = (i < c) ? bk[i] : nc;
    uint4 v0 = H4[(size_t)s * 16 + sub];
    acc8(a, v0, i < c);
  }

  float dn = an ? dinv[nc] : 0.f;
  float4 b0 = ((const float4*)bias)[sub * 2];
  float4 b1 = ((const float4*)bias)[sub * 2 + 1];
  float o[8];
  o[0] = tanhf(a[0]*dn + b0.x); o[1] = tanhf(a[1]*dn + b0.y);
  o[2] = tanhf(a[2]*dn + b0.z); o[3] = tanhf(a[3]*dn + b0.w);
  o[4] = tanhf(a[4]*dn + b1.x); o[5] = tanhf(a[5]*dn + b1.y);
  o[6] = tanhf(a[6]*dn + b1.z); o[7] = tanhf(a[7]*dn + b1.w);
  if (an) {
    float4* dst0 = (float4*)(OUT + (size_t)node * 128 + sub * 8);
    dst0[0] = make_float4(o[0], o[1], o[2], o[3]);
    dst0[1] = make_float4(o[4], o[5], o[6], o[7]);
  }
  if (FC) {
    float4 w0 = ((const float4*)Wfc)[sub * 2];
    float4 w1 = ((const float4*)Wfc)[sub * 2 + 1];
    float p = o[0]*w0.x + o[1]*w0.y + o[2]*w0.z + o[3]*w0.w
            + o[4]*w1.x + o[5]*w1.y + o[6]*w1.z + o[7]*w1.w;
    p += __shfl_down(p, 8, 16);
    p += __shfl_down(p, 4, 16);
    p += __shfl_down(p, 2, 16);
    p += __shfl_down(p, 1, 16);
    if (an && sub == 0) OUTV[node] = 1.0f / (1.0f + expf(-(p + bfc[0])));
  }
}

// ---------------- launch ----------------

extern "C" void kernel_launch(void* const* d_in, const int* in_sizes, int n_in,
                              void* d_out, int out_size, void* d_ws, size_t ws_size,
                              hipStream_t stream) {
  const float* x   = (const float*)d_in[0];
  const int*   ei  = (const int*)d_in[1];
  const float* W1  = (const float*)d_in[2];
  const float* b1  = (const float*)d_in[3];
  const float* W2  = (const float*)d_in[4];
  const float* b2  = (const float*)d_in[5];
  const float* Wfc = (const float*)d_in[6];
  const float* bfc = (const float*)d_in[7];

  const int N = in_sizes[0] / 128;
  const int E = in_sizes[1] / 2;
  const int* src = ei;
  const int* dst = ei + E;

  float* out = (float*)d_out;      // [N] sigmoid output
  float* emb = out + N;            // [N*128] embeddings; doubles as layer-1 act scratch

  char* ws = (char*)d_ws;
  auto take = [&](size_t bytes) { char* p = ws; ws += (bytes + 255) & ~(size_t)255; return p; };
  int*    cnt    = (int*)   take((size_t)N * 4);
  float*  dinv   = (float*) take((size_t)N * 4);
  int*    aux    = (int*)   take(64 * 4);
  int*    bucket = (int*)   take((size_t)N * CAP * 4);
  ushort* bufH   = (ushort*)take((size_t)N * 128 * 2);   // bf16 h*dinv
  int2*   part   = (int2*)bufH;    // consumed by k_bucket2 before gemm writes bufH

  const int ntiles = (N + 15) / 16;
  const int aggBlocks = (N + 15) / 16;

  hipMemsetAsync(cnt, 0, (size_t)N * 4, stream);
  hipMemsetAsync(aux, 0, 64 * 4, stream);

  k_hist<<<1024, 256, 0, stream>>>(dst, aux, E);
  k_scan<<<1, 64, 0, stream>>>(aux);
  k_partition<<<(E + EPB - 1) / EPB, 256, 0, stream>>>(src, dst, aux, part, E);
  k_bucket2<<<(E + 255) / 256, 256, 0, stream>>>(part, cnt, bucket, E);
  k_dinv<<<(N + 255) / 256, 256, 0, stream>>>(cnt, dinv, N);

  // layer 1
  k_gemm_mfma<<<512, 256, 0, stream>>>(x, W1, dinv, bufH, N, ntiles);
  k_agg4<false><<<aggBlocks, 256, 0, stream>>>(bufH, cnt, bucket, dinv, b1,
                                               nullptr, nullptr, emb, nullptr, N);
  // layer 2 (+ fused FC head)
  k_gemm_mfma<<<512, 256, 0, stream>>>(emb, W2, dinv, bufH, N, ntiles);
  k_agg4<true><<<aggBlocks, 256, 0, stream>>>(bufH, cnt, bucket, dinv, b2,
                                              Wfc, bfc, emb, out, N);
}

// Round 6
// 413.025 us; speedup vs baseline: 1.2120x; 1.0594x over previous
//
#include <hip/hip_runtime.h>
#include <math.h>

#define CAP 96            // max in-degree stored; Poisson(16) tail beyond 96 ~ 1e-42
#define NR 16             // dst ranges of 6250 nodes; range r -> XCD r%8
#define EPB 4096          // edges per partition block (16/thread)
#define PCAP 112640       // per-range part capacity (E/NR=100k, sigma~306 -> 39-sigma margin)

typedef unsigned int uint;
typedef unsigned short ushort;
typedef __attribute__((ext_vector_type(8))) short bf16x8;
typedef __attribute__((ext_vector_type(4))) float f32x4;

__device__ __forceinline__ ushort f2bf(float f) {   // RNE fp32 -> bf16
  union { float f; uint u; } v; v.f = f;
  uint u = v.u;
  return (ushort)((u + 0x7fffu + ((u >> 16) & 1u)) >> 16);
}
__device__ __forceinline__ float bflo(uint p) {
  union { uint u; float f; } v; v.u = p << 16; return v.f;
}
__device__ __forceinline__ float bfhi(uint p) {
  union { uint u; float f; } v; v.u = p & 0xffff0000u; return v.f;
}
__device__ __forceinline__ uint pk2(float a, float b) {
  return (uint)f2bf(a) | ((uint)f2bf(b) << 16);
}
__device__ __forceinline__ uint pk2r(float a, float b, float& ra, float& rb) {
  ushort ha = f2bf(a), hb = f2bf(b);
  union { uint u; float f; } va, vb;
  va.u = (uint)ha << 16; vb.u = (uint)hb << 16;
  ra = a - va.f; rb = b - vb.f;
  return (uint)ha | ((uint)hb << 16);
}
__device__ __forceinline__ int drange(int d) {      // d / 6250 via magic mul
  return (int)(((unsigned long long)(uint)d * 687195ull) >> 32);
}

// ---------------- partition: scatter edges into 16 fixed-capacity range streams ----------------

__global__ __launch_bounds__(256) void k_partition(const int* __restrict__ src,
    const int* __restrict__ dst, int* __restrict__ cur,
    int2* __restrict__ part, int E) {
  __shared__ int lcnt[NR * 256];
  __shared__ int basev[NR];
  const int t = threadIdx.x;
  const int b0 = blockIdx.x * EPB;
  #pragma unroll
  for (int r = 0; r < NR; ++r) lcnt[r * 256 + t] = 0;
  __syncthreads();
  int es[16], ed[16];
  #pragma unroll
  for (int j = 0; j < 16; ++j) {
    int e = b0 + j * 256 + t;
    int d = (e < E) ? dst[e] : -1;
    es[j] = (e < E) ? src[e] : 0;
    ed[j] = d;
    if (d >= 0) lcnt[drange(d) * 256 + t]++;        // only thread t touches column t
  }
  __syncthreads();
  if (t < NR) {                                     // exclusive scan over threads
    int run = 0;
    #pragma unroll 8
    for (int k = 0; k < 256; ++k) { int v = lcnt[t * 256 + k]; lcnt[t * 256 + k] = run; run += v; }
    basev[t] = atomicAdd(cur + t, run);
  }
  __syncthreads();
  #pragma unroll
  for (int j = 0; j < 16; ++j) {
    int d = ed[j];
    if (d >= 0) {
      int r = drange(d);
      int off = basev[r] + lcnt[r * 256 + t]++;
      if (off < PCAP) part[(size_t)r * PCAP + off] = make_int2(es[j], d);
    }
  }
}

// ---------------- bucket build, XCD-pinned by dst range ----------------
// Range r is processed only by blocks with blockIdx&7 == r&7: with round-robin
// block->XCD dispatch these share one XCD, so the range's 2.4MB bucket slice +
// cnt slice stay in that XCD's L2 and partial-line writes merge before eviction.
// Correct under ANY dispatch mapping (each edge processed exactly once).

__global__ __launch_bounds__(256) void k_bucket2(const int2* __restrict__ part,
    const int* __restrict__ cur, int* __restrict__ cnt, int* __restrict__ bucket) {
  const int t = threadIdx.x;
  const int xcd = blockIdx.x & 7;
  const int slot = blockIdx.x >> 3;
  const int S = (gridDim.x >> 3) * 256;
  for (int rr = xcd; rr < NR; rr += 8) {
    int cE = min(cur[rr], PCAP);
    const int2* p = part + (size_t)rr * PCAP;
    int e = slot * 256 + t;
    for (; e + 3 * S < cE; e += 4 * S) {
      int2 p0 = p[e], p1 = p[e + S], p2 = p[e + 2 * S], p3 = p[e + 3 * S];
      int k0 = atomicAdd(cnt + p0.y, 1);
      int k1 = atomicAdd(cnt + p1.y, 1);
      int k2 = atomicAdd(cnt + p2.y, 1);
      int k3 = atomicAdd(cnt + p3.y, 1);
      if (k0 < CAP) bucket[(size_t)p0.y * CAP + k0] = p0.x;
      if (k1 < CAP) bucket[(size_t)p1.y * CAP + k1] = p1.x;
      if (k2 < CAP) bucket[(size_t)p2.y * CAP + k2] = p2.x;
      if (k3 < CAP) bucket[(size_t)p3.y * CAP + k3] = p3.x;
    }
    for (; e < cE; e += S) {
      int2 pe = p[e];
      int k = atomicAdd(cnt + pe.y, 1);
      if (k < CAP) bucket[(size_t)pe.y * CAP + k] = pe.x;
    }
  }
}

__global__ __launch_bounds__(256) void k_dinv(const int* __restrict__ cnt,
                                              float* __restrict__ dinv, int n) {
  int i = blockIdx.x * 256 + threadIdx.x;
  if (i < n) dinv[i] = rsqrtf((float)cnt[i] + 1.0f);   // +1 self-loop
}

// ---------------- MFMA GEMM: H = (X @ W) * dinv[row], bf16 out ----------------

__global__ __launch_bounds__(256) void k_gemm_mfma(const float* __restrict__ X,
    const float* __restrict__ W, const float* __restrict__ dinv,
    ushort* __restrict__ H, int n, int ntiles) {
  const int lane = threadIdx.x & 63;
  const int quad = lane >> 4;
  const int sub  = lane & 15;
  const int wid    = (blockIdx.x * 256 + threadIdx.x) >> 6;
  const int nwaves = (gridDim.x * 256) >> 6;

  union { bf16x8 v; uint u[4]; } Bh[4][8];
  #pragma unroll
  for (int ki = 0; ki < 4; ++ki) {
    #pragma unroll
    for (int ct = 0; ct < 8; ++ct) {
      const float* wp = W + (ki * 32 + quad * 8) * 128 + ct * 16 + sub;
      Bh[ki][ct].u[0] = pk2(wp[0],   wp[128]);
      Bh[ki][ct].u[1] = pk2(wp[256], wp[384]);
      Bh[ki][ct].u[2] = pk2(wp[512], wp[640]);
      Bh[ki][ct].u[3] = pk2(wp[768], wp[896]);
    }
  }

  for (int tile = wid; tile < ntiles; tile += nwaves) {
    int base = tile * 16;
    int row  = base + sub;
    if (row >= n) row = n - 1;
    const float* xp = X + (size_t)row * 128 + quad * 8;

    f32x4 acc[8];
    #pragma unroll
    for (int ct = 0; ct < 8; ++ct) acc[ct] = (f32x4){0.f, 0.f, 0.f, 0.f};

    #pragma unroll
    for (int ki = 0; ki < 4; ++ki) {
      float4 xa = *(const float4*)(xp + ki * 32);
      float4 xb = *(const float4*)(xp + ki * 32 + 4);
      union { bf16x8 v; uint u[4]; } ah, al;
      float r0,r1,r2,r3,r4,r5,r6,r7;
      ah.u[0] = pk2r(xa.x, xa.y, r0, r1);
      ah.u[1] = pk2r(xa.z, xa.w, r2, r3);
      ah.u[2] = pk2r(xb.x, xb.y, r4, r5);
      ah.u[3] = pk2r(xb.z, xb.w, r6, r7);
      al.u[0] = pk2(r0, r1);
      al.u[1] = pk2(r2, r3);
      al.u[2] = pk2(r4, r5);
      al.u[3] = pk2(r6, r7);
      #pragma unroll
      for (int ct = 0; ct < 8; ++ct) {
        acc[ct] = __builtin_amdgcn_mfma_f32_16x16x32_bf16(ah.v, Bh[ki][ct].v, acc[ct], 0, 0, 0);
        acc[ct] = __builtin_amdgcn_mfma_f32_16x16x32_bf16(al.v, Bh[ki][ct].v, acc[ct], 0, 0, 0);
      }
    }

    float dv[4];
    #pragma unroll
    for (int r = 0; r < 4; ++r) {
      int rr = base + quad * 4 + r;
      dv[r] = (rr < n) ? dinv[rr] : 0.f;
    }
    #pragma unroll
    for (int ct = 0; ct < 8; ++ct) {
      #pragma unroll
      for (int r = 0; r < 4; ++r) {
        int rr = base + quad * 4 + r;
        if (rr < n)
          H[(size_t)rr * 128 + ct * 16 + sub] = f2bf(acc[ct][r] * dv[r]);
      }
    }
  }
}

// ---------------- aggregation: 4 nodes/wave, 16 lanes x dwordx4 per row ----------------

__device__ __forceinline__ void acc8(float* a, uint4 v, bool act) {
  if (act) {
    a[0] += bflo(v.x); a[1] += bfhi(v.x); a[2] += bflo(v.y); a[3] += bfhi(v.y);
    a[4] += bflo(v.z); a[5] += bfhi(v.z); a[6] += bflo(v.w); a[7] += bfhi(v.w);
  }
}

template <bool FC>
__global__ __launch_bounds__(256) void k_agg4(const ushort* __restrict__ H,
    const int* __restrict__ cnt, const int* __restrict__ bucket,
    const float* __restrict__ dinv, const float* __restrict__ bias,
    const float* __restrict__ Wfc, const float* __restrict__ bfc,
    float* __restrict__ OUT, float* __restrict__ OUTV, int n) {
  const int wave = (blockIdx.x * 256 + threadIdx.x) >> 6;
  const int lane = threadIdx.x & 63;
  const int g = lane >> 4, sub = lane & 15;
  const int node = wave * 4 + g;
  const bool an = node < n;
  const int nc = an ? node : 0;
  const uint4* H4 = (const uint4*)H;

  uint4 v = H4[(size_t)nc * 16 + sub];
  float a[8] = {bflo(v.x),bfhi(v.x),bflo(v.y),bfhi(v.y),
                bflo(v.z),bfhi(v.z),bflo(v.w),bfhi(v.w)};
  int c = an ? min(cnt[nc], CAP) : 0;
  int cmax = max(c, __shfl_xor(c, 16)); cmax = max(cmax, __shfl_xor(cmax, 32));
  const int* bk = bucket + (size_t)nc * CAP;

  int i = 0;
  for (; i + 4 <= cmax; i += 4) {
    int s0 = (i     < c) ? bk[i]     : nc;
    int s1 = (i + 1 < c) ? bk[i + 1] : nc;
    int s2 = (i + 2 < c) ? bk[i + 2] : nc;
    int s3 = (i + 3 < c) ? bk[i + 3] : nc;
    uint4 v0 = H4[(size_t)s0 * 16 + sub];
    uint4 v1 = H4[(size_t)s1 * 16 + sub];
    uint4 v2 = H4[(size_t)s2 * 16 + sub];
    uint4 v3 = H4[(size_t)s3 * 16 + sub];
    acc8(a, v0, i < c); acc8(a, v1, i + 1 < c);
    acc8(a, v2, i + 2 < c); acc8(a, v3, i + 3 < c);
  }
  for (; i < cmax; ++i) {
    int s = (i < c) ? bk[i] : nc;
    uint4 v0 = H4[(size_t)s * 16 + sub];
    acc8(a, v0, i < c);
  }

  float dn = an ? dinv[nc] : 0.f;
  float4 b0 = ((const float4*)bias)[sub * 2];
  float4 b1 = ((const float4*)bias)[sub * 2 + 1];
  float o[8];
  o[0] = tanhf(a[0]*dn + b0.x); o[1] = tanhf(a[1]*dn + b0.y);
  o[2] = tanhf(a[2]*dn + b0.z); o[3] = tanhf(a[3]*dn + b0.w);
  o[4] = tanhf(a[4]*dn + b1.x); o[5] = tanhf(a[5]*dn + b1.y);
  o[6] = tanhf(a[6]*dn + b1.z); o[7] = tanhf(a[7]*dn + b1.w);
  if (an) {
    float4* dst0 = (float4*)(OUT + (size_t)node * 128 + sub * 8);
    dst0[0] = make_float4(o[0], o[1], o[2], o[3]);
    dst0[1] = make_float4(o[4], o[5], o[6], o[7]);
  }
  if (FC) {
    float4 w0 = ((const float4*)Wfc)[sub * 2];
    float4 w1 = ((const float4*)Wfc)[sub * 2 + 1];
    float p = o[0]*w0.x + o[1]*w0.y + o[2]*w0.z + o[3]*w0.w
            + o[4]*w1.x + o[5]*w1.y + o[6]*w1.z + o[7]*w1.w;
    p += __shfl_down(p, 8, 16);
    p += __shfl_down(p, 4, 16);
    p += __shfl_down(p, 2, 16);
    p += __shfl_down(p, 1, 16);
    if (an && sub == 0) OUTV[node] = 1.0f / (1.0f + expf(-(p + bfc[0])));
  }
}

// ---------------- launch ----------------

extern "C" void kernel_launch(void* const* d_in, const int* in_sizes, int n_in,
                              void* d_out, int out_size, void* d_ws, size_t ws_size,
                              hipStream_t stream) {
  const float* x   = (const float*)d_in[0];
  const int*   ei  = (const int*)d_in[1];
  const float* W1  = (const float*)d_in[2];
  const float* b1  = (const float*)d_in[3];
  const float* W2  = (const float*)d_in[4];
  const float* b2  = (const float*)d_in[5];
  const float* Wfc = (const float*)d_in[6];
  const float* bfc = (const float*)d_in[7];

  const int N = in_sizes[0] / 128;
  const int E = in_sizes[1] / 2;
  const int* src = ei;
  const int* dst = ei + E;

  float* out = (float*)d_out;      // [N] sigmoid output
  float* emb = out + N;            // [N*128] embeddings; layer-1 act scratch first

  char* ws = (char*)d_ws;
  auto take = [&](size_t bytes) { char* p = ws; ws += (bytes + 255) & ~(size_t)255; return p; };
  int*    cnt    = (int*)   take((size_t)N * 4);
  float*  dinv   = (float*) take((size_t)N * 4);
  int*    cur    = (int*)   take(64 * 4);
  int*    bucket = (int*)   take((size_t)N * CAP * 4);
  ushort* bufH   = (ushort*)take((size_t)N * 128 * 2);   // bf16 h*dinv
  int2*   part   = (int2*)bufH;    // 16*PCAP int2 = 14.4MB < 25.6MB; consumed before gemm1 writes

  const int ntiles = (N + 15) / 16;
  const int aggBlocks = (N + 15) / 16;

  hipMemsetAsync(cnt, 0, (size_t)N * 4, stream);
  hipMemsetAsync(cur, 0, 64 * 4, stream);

  k_partition<<<(E + EPB - 1) / EPB, 256, 0, stream>>>(src, dst, cur, part, E);
  k_bucket2<<<2048, 256, 0, stream>>>(part, cur, cnt, bucket);
  k_dinv<<<(N + 255) / 256, 256, 0, stream>>>(cnt, dinv, N);

  // layer 1
  k_gemm_mfma<<<512, 256, 0, stream>>>(x, W1, dinv, bufH, N, ntiles);
  k_agg4<false><<<aggBlocks, 256, 0, stream>>>(bufH, cnt, bucket, dinv, b1,
                                               nullptr, nullptr, emb, nullptr, N);
  // layer 2 (+ fused FC head)
  k_gemm_mfma<<<512, 256, 0, stream>>>(emb, W2, dinv, bufH, N, ntiles);
  k_agg4<true><<<aggBlocks, 256, 0, stream>>>(bufH, cnt, bucket, dinv, b2,
                                              Wfc, bfc, emb, out, N);
}